// Round 2
// baseline (2670.654 us; speedup 1.0000x reference)
//
#include <hip/hip_runtime.h>

#define SEQ   1024
#define BATCH 8192
#define HID   50
#define BT    4            // batch rows per wave/block
#define NTIL  13           // gate tiles of 16 (208 >= 200)
#define GS    212          // gate row stride in floats (212 % 8 == 4 -> conflict-free)
#define NCH   64           // chunks of 16 steps
#define CHS   16           // steps per x chunk
#define CHF   (CHS*BT*3)   // floats per chunk = 192

typedef _Float16 half8 __attribute__((ext_vector_type(8)));
typedef float    f32x4 __attribute__((ext_vector_type(4)));

__device__ __forceinline__ float sigm(float x){
  return __builtin_amdgcn_rcpf(1.0f + __builtin_amdgcn_exp2f(-1.44269504f * x));
}
__device__ __forceinline__ float tanh_f(float x){
  // tanh(x) = 1 - 2/(1+2^(2x*log2e)); handles +-inf via rcp(inf)=0
  return 1.0f - 2.0f * __builtin_amdgcn_rcpf(1.0f + __builtin_amdgcn_exp2f(2.88539008f * x));
}
__device__ __forceinline__ void wsync(){ __builtin_amdgcn_wave_barrier(); }

// x chunk load: float f = lane + 64*u of chunk cg; layout [step s][b_local*3+comp]
#define XLOAD(cg, dst, u) {                                                   \
    int f_ = lane + 64*(u); int s_ = f_/12; int e_ = f_ - s_*12;              \
    dst = x[((size_t)(CHS*(cg)+s_)*BATCH + b0)*3 + e_]; }

__global__ __launch_bounds__(64, 1)
void lstm_wave(const float* __restrict__ x,
               const float* __restrict__ W_ih,
               const float* __restrict__ W_hh,
               const float* __restrict__ b_ih,
               const float* __restrict__ b_hh,
               const float* __restrict__ fc_w,
               const float* __restrict__ fc_b,
               float* __restrict__ out)
{
  // A-fragment-layout h buffer: [kh][grp][r16][i] halves, flat 1024 (2 KB).
  // ds_read_b128 at byte addr lane*16 (+1024 for kh1) -> contiguous, conflict-free.
  __shared__ _Float16 A_lds[1024];
  __shared__ float gate[BT][GS];     // gate preactivations, rows = batch
  __shared__ float xb[2*CHF];        // x double buffer [2][16 steps][12]
  __shared__ float hf[BT][HID];      // final-step h (fp32)

  const int lane = threadIdx.x;      // 0..63
  const int r16  = lane & 15;
  const int grp  = lane >> 4;
  const int b0   = blockIdx.x * BT;

  // ---- one-time: B fragments in registers (fp16), with x/bias folded in ----
  // B[k][g]: k<50 -> W_hh[g][k]; k=50..52 -> W_ih[g][k-50]; k=53 -> b_ih+b_hh; else 0
  half8 Bf[NTIL][2];
  #pragma unroll
  for (int tile = 0; tile < NTIL; ++tile) {
    int g = tile*16 + r16;
    bool gok = (g < 4*HID);
    #pragma unroll
    for (int kh = 0; kh < 2; ++kh) {
      half8 f;
      #pragma unroll
      for (int i = 0; i < 8; ++i) {
        int k = kh*32 + grp*8 + i;
        float w = 0.0f;
        if (gok) {
          if (k < 50)       w = W_hh[g*HID + k];
          else if (k < 53)  w = W_ih[g*3 + (k-50)];
          else if (k == 53) w = b_ih[g] + b_hh[g];
        }
        f[i] = (_Float16)w;
      }
      Bf[tile][kh] = f;
    }
  }

  // ---- init: zero A_lds (h0 = 0, padding = 0), set the k=53 "1.0" slot ----
  #pragma unroll
  for (int u = 0; u < 16; ++u) A_lds[lane + 64*u] = (_Float16)0.0f;
  if (lane < BT) A_lds[(96 + lane)*8 + 5] = (_Float16)1.0f;  // kh1,grp2,i=5

  // ---- x prefetch prologue: chunks 0,1 -> LDS; issue chunk 2 ----
  float xr0, xr1, xr2;
  XLOAD(0, xr0, 0); XLOAD(0, xr1, 1); XLOAD(0, xr2, 2);
  xb[lane] = xr0; xb[lane+64] = xr1; xb[lane+128] = xr2;
  XLOAD(1, xr0, 0); XLOAD(1, xr1, 1); XLOAD(1, xr2, 2);
  xb[CHF+lane] = xr0; xb[CHF+lane+64] = xr1; xb[CHF+lane+128] = xr2;
  XLOAD(2, xr0, 0); XLOAD(2, xr1, 1); XLOAD(2, xr2, 2);

  // x for step 0 into A_lds (k=50..52 slots), lanes 0..11
  if (lane < BT*3) {
    int bl = lane/3, cm = lane - bl*3;
    A_lds[(96 + bl)*8 + 2 + cm] = (_Float16)xb[lane];
  }
  wsync();

  float c[4] = {0.f, 0.f, 0.f, 0.f};

  for (int tc = 0; tc < NCH; ++tc) {
    if (tc > 0) {
      // regs hold chunk tc+1 (issued at tc-1): commit to LDS, issue chunk tc+2
      int p = (tc + 1) & 1;
      xb[p*CHF + lane]       = xr0;
      xb[p*CHF + lane +  64] = xr1;
      xb[p*CHF + lane + 128] = xr2;
      if (tc + 2 < NCH) {
        XLOAD(tc+2, xr0, 0); XLOAD(tc+2, xr1, 1); XLOAD(tc+2, xr2, 2);
      }
    }
    #pragma unroll 1
    for (int ts = 0; ts < CHS; ++ts) {
      const int t = tc*CHS + ts;

      // ---- MFMA phase: gates = [h | x | 1] . B ----
      half8 a0 = *(const half8*)&A_lds[lane*8];        // kh0
      half8 a1 = *(const half8*)&A_lds[512 + lane*8];  // kh1
      #pragma unroll
      for (int tile = 0; tile < NTIL; ++tile) {
        f32x4 acc = {0.f, 0.f, 0.f, 0.f};
        acc = __builtin_amdgcn_mfma_f32_16x16x32_f16(a0, Bf[tile][0], acc, 0, 0, 0);
        acc = __builtin_amdgcn_mfma_f32_16x16x32_f16(a1, Bf[tile][1], acc, 0, 0, 0);
        if (grp == 0) {  // D rows 0..3 = real batch rows
          #pragma unroll
          for (int i = 0; i < 4; ++i)
            gate[i][tile*16 + r16] = acc[i];
        }
      }
      wsync();

      // ---- elementwise update: 200 items, c in registers ----
      const bool last = (t == SEQ-1);
      #pragma unroll
      for (int k = 0; k < 4; ++k) {
        int item = lane + 64*k;
        if (item < BT*HID) {
          int b = (item*82) >> 12;     // /50, exact for item<350
          int j = item - b*50;
          float pi = gate[b][j];
          float pf = gate[b][ 50+j];
          float pg = gate[b][100+j];
          float po = gate[b][150+j];
          float si = sigm(pi), sf = sigm(pf), sg = tanh_f(pg), so = sigm(po);
          float cn = sf*c[k] + si*sg;
          c[k] = cn;
          float h = so * tanh_f(cn);
          int kh = j >> 5, g2 = (j & 31) >> 3, ii = j & 7;
          A_lds[kh*512 + g2*128 + b*8 + ii] = (_Float16)h;
          if (last) hf[b][j] = h;
        }
      }
      // x for step t+1 into A_lds slots (harmless garbage at t=1023)
      if (lane < BT*3) {
        int tn = t + 1;
        int p = (tn >> 4) & 1, s = tn & 15;
        int bl = lane/3, cm = lane - bl*3;
        float xv = xb[p*CHF + s*12 + lane];
        A_lds[(96 + bl)*8 + 2 + cm] = (_Float16)xv;
      }
      wsync();
    }
  }

  __syncthreads();
  // ---- epilogue: out[b] = fc_w . h_final + fc_b ----
  if (lane < BT) {
    float s = fc_b[0];
    #pragma unroll
    for (int j = 0; j < HID; ++j) s += fc_w[j] * hf[lane][j];
    out[b0 + lane] = s;
  }
}

extern "C" void kernel_launch(void* const* d_in, const int* in_sizes, int n_in,
                              void* d_out, int out_size, void* d_ws, size_t ws_size,
                              hipStream_t stream)
{
  const float* x    = (const float*)d_in[0];
  const float* W_ih = (const float*)d_in[1];
  const float* W_hh = (const float*)d_in[2];
  const float* b_ih = (const float*)d_in[3];
  const float* b_hh = (const float*)d_in[4];
  const float* fc_w = (const float*)d_in[5];
  const float* fc_b = (const float*)d_in[6];
  lstm_wave<<<BATCH/BT, 64, 0, stream>>>(x, W_ih, W_hh, b_ih, b_hh, fc_w, fc_b,
                                         (float*)d_out);
}

// Round 3
// 1372.527 us; speedup vs baseline: 1.9458x; 1.9458x over previous
//
#include <hip/hip_runtime.h>

#define SEQ   1024
#define BATCH 8192
#define HID   50
#define NTIL  13           // 13 gate tiles of 16 cols (208 >= 200)
#define GSTR  5            // gateT col stride in dwords (4 rows + 1 pad)
#define CHS   16           // steps per x chunk
#define NCH   (SEQ/CHS)
#define CHF   192          // floats per wave-chunk = 16 steps * 4 rows * 3

typedef _Float16 half8 __attribute__((ext_vector_type(8)));
typedef float    f32x4 __attribute__((ext_vector_type(4)));

__device__ __forceinline__ void wsync(){ __builtin_amdgcn_wave_barrier(); }

// x chunk load into 3 regs: flat f = lane + 64u -> step s=f/12, elem e=f%12
#define XLOAD(cg) {                                                          \
    int f0 = lane, f1 = lane + 64, f2 = lane + 128;                          \
    xr0 = x[(size_t)((cg)*CHS + f0/12)*(BATCH*3) + (size_t)b0w*3 + (f0%12)]; \
    xr1 = x[(size_t)((cg)*CHS + f1/12)*(BATCH*3) + (size_t)b0w*3 + (f1%12)]; \
    xr2 = x[(size_t)((cg)*CHS + f2/12)*(BATCH*3) + (size_t)b0w*3 + (f2%12)]; }

__global__ __launch_bounds__(256, 2)
void lstm_w4(const float* __restrict__ x,
             const float* __restrict__ W_ih,
             const float* __restrict__ W_hh,
             const float* __restrict__ b_ih,
             const float* __restrict__ b_hh,
             const float* __restrict__ fc_w,
             const float* __restrict__ fc_b,
             float* __restrict__ out)
{
  // per-wave regions, no cross-wave communication -> zero barriers in the loop
  __shared__ _Float16 A_lds[4][1024];     // MFMA-A-layout [kh][grp][r16][i], 2 KB/wave
  __shared__ float    gT[4][208*GSTR];    // gateT[col][row], quad-interleaved cols
  __shared__ float    xb[4][2][CHF];      // x double buffer
  __shared__ float    hf[4][4][HID];      // final-step h (fp32)

  const int tid  = threadIdx.x;
  const int w    = tid >> 6;
  const int lane = tid & 63;
  const int r16  = lane & 15;
  const int grp  = lane >> 4;
  const int b0w  = blockIdx.x * 16 + w * 4;     // this wave's batch base

  _Float16* Aw = A_lds[w];
  float*    gw = gT[w];

  // ---- one-time: B fragments (fp16), cols permuted c=4j+gate, pre-scaled ----
  // B[k][c]: k<50 -> W_hh * sc ; k=50..52 -> W_ih * sc ; k=53 -> (b_ih+b_hh)*sc
  // sc = -log2e for i,f,o (sigmoid via exp2), +2log2e for g (tanh via exp2)
  const float L2E = 1.44269504088896f;
  half8 Bf[NTIL][2];
  #pragma unroll
  for (int tile = 0; tile < NTIL; ++tile) {
    const int  c  = tile*16 + r16;
    const bool ok = (c < 4*HID);
    const int  j  = c >> 2, gi = c & 3;
    const int  go = gi*HID + (ok ? j : 0);      // original row in i,f,g,o order
    const float sc = (gi == 2) ? (2.0f*L2E) : (-L2E);
    #pragma unroll
    for (int kh = 0; kh < 2; ++kh) {
      half8 f;
      #pragma unroll
      for (int i = 0; i < 8; ++i) {
        const int k = kh*32 + grp*8 + i;
        float wv = 0.0f;
        if (ok) {
          if (k < HID)      wv = W_hh[go*HID + k] * sc;
          else if (k < 53)  wv = W_ih[go*3 + (k-50)] * sc;
          else if (k == 53) wv = (b_ih[go] + b_hh[go]) * sc;
        }
        f[i] = (_Float16)wv;
      }
      Bf[tile][kh] = f;
    }
  }

  // ---- init: zero A (h0=0, pad rows 4..15 = 0), set k=53 "1.0" slot ----
  #pragma unroll
  for (int u = 0; u < 16; ++u) Aw[lane + 64*u] = (_Float16)0.0f;
  wsync();
  if (lane < 4) Aw[(96 + lane)*8 + 5] = (_Float16)1.0f;   // k=53 -> kh1,grp2,i5

  // ---- per-lane elementwise addressing, hoisted out of the t-loop ----
  // item m = lane + 64k : j = m>>2 (hidden), b = m&3 (row). k=0..2 full, k=3: lane<8
  int rdi[4], hwi[4], mj[4], mb[4];
  #pragma unroll
  for (int k = 0; k < 4; ++k) {
    const int m = lane + 64*k;
    const int j = m >> 2, b = m & 3;
    mj[k] = j; mb[k] = b;
    rdi[k] = 20*j + b;                                   // + {0,5,10,15} for i,f,g,o
    hwi[k] = (j>>5)*512 + ((j&31)>>3)*128 + b*8 + (j&7); // A-slot of h[b][j]
  }

  // ---- x prefetch prologue: chunks 0,1 -> LDS; issue chunk 2 ----
  float xr0, xr1, xr2;
  XLOAD(0); xb[w][0][lane]=xr0; xb[w][0][lane+64]=xr1; xb[w][0][lane+128]=xr2;
  XLOAD(1); xb[w][1][lane]=xr0; xb[w][1][lane+64]=xr1; xb[w][1][lane+128]=xr2;
  XLOAD(2);
  if (lane < 12) {                                       // x for step 0
    int bl = (lane*11) >> 5, cm = lane - bl*3;
    Aw[(96+bl)*8 + 2 + cm] = (_Float16)xb[w][0][lane];
  }
  wsync();

  float cst[4] = {0.f, 0.f, 0.f, 0.f};

  for (int tc2 = 0; tc2 < NCH; ++tc2) {
    if (tc2 > 0) {
      const int p = (tc2 + 1) & 1;     // commit chunk tc2+1 (issued at tc2-1)
      xb[w][p][lane]     = xr0;
      xb[w][p][lane+64]  = xr1;
      xb[w][p][lane+128] = xr2;
      if (tc2 + 2 < NCH) { XLOAD(tc2+2); }
    }
    #pragma unroll 1
    for (int ts = 0; ts < CHS; ++ts) {
      const int t = tc2*CHS + ts;

      // ---- MFMA: gates = [h | x | 1] . B  (A rows 0..3 real, 4..15 zero) ----
      const half8 a0 = *(const half8*)&Aw[lane*8];
      const half8 a1 = *(const half8*)&Aw[512 + lane*8];
      #pragma unroll
      for (int tile = 0; tile < NTIL; ++tile) {
        f32x4 acc = {0.f, 0.f, 0.f, 0.f};
        acc = __builtin_amdgcn_mfma_f32_16x16x32_f16(a0, Bf[tile][0], acc, 0, 0, 0);
        acc = __builtin_amdgcn_mfma_f32_16x16x32_f16(a1, Bf[tile][1], acc, 0, 0, 0);
        if (grp == 0) {                  // D rows 0..3 = batch, col r16 of tile
          float* p = &gw[(tile*16 + r16)*GSTR];
          p[0] = acc[0]; p[1] = acc[1]; p[2] = acc[2]; p[3] = acc[3];
        }
      }

      // ---- elementwise: 200 items; gates pre-scaled so sigm/tanh are lean ----
      const bool last = (t == SEQ-1);
      #pragma unroll
      for (int k = 0; k < 4; ++k) {
        if (k < 3 || lane < 8) {
          const float* rp = &gw[rdi[k]];
          const float vi = rp[0], vf = rp[5], vg = rp[10], vo = rp[15];
          const float si = __builtin_amdgcn_rcpf(1.0f + __builtin_amdgcn_exp2f(vi));
          const float sf = __builtin_amdgcn_rcpf(1.0f + __builtin_amdgcn_exp2f(vf));
          const float so = __builtin_amdgcn_rcpf(1.0f + __builtin_amdgcn_exp2f(vo));
          const float sg = __builtin_fmaf(-2.0f,
                             __builtin_amdgcn_rcpf(1.0f + __builtin_amdgcn_exp2f(vg)), 1.0f);
          const float cn = __builtin_fmaf(sf, cst[k], si*sg);
          cst[k] = cn;
          const float ec = __builtin_amdgcn_exp2f(cn * (2.0f*L2E));
          const float th = __builtin_fmaf(-2.0f, __builtin_amdgcn_rcpf(1.0f + ec), 1.0f);
          const float h  = so * th;
          Aw[hwi[k]] = (_Float16)h;
          if (last) hf[w][mb[k]][mj[k]] = h;
        }
      }

      // ---- x for step t+1 into A slots (t=1023: harmless dead write) ----
      if (lane < 12) {
        const int tn = t + 1;
        const int p = (tn >> 4) & 1, s = tn & 15;
        const int bl = (lane*11) >> 5, cm = lane - bl*3;
        Aw[(96+bl)*8 + 2 + cm] = (_Float16)xb[w][p][s*12 + lane];
      }
      wsync();
    }
  }

  // ---- epilogue (per wave): out[b] = fc_w . h_final[b] + fc_b ----
  float pa = 0.0f;
  #pragma unroll
  for (int m2 = 0; m2 < 4; ++m2) {
    const int j = r16 + 16*m2;
    if (j < HID) pa += fc_w[j] * hf[w][grp][j];
  }
  pa += __shfl_xor(pa, 1);
  pa += __shfl_xor(pa, 2);
  pa += __shfl_xor(pa, 4);
  pa += __shfl_xor(pa, 8);
  if (r16 == 0) out[b0w + grp] = pa + fc_b[0];
}

extern "C" void kernel_launch(void* const* d_in, const int* in_sizes, int n_in,
                              void* d_out, int out_size, void* d_ws, size_t ws_size,
                              hipStream_t stream)
{
  const float* x    = (const float*)d_in[0];
  const float* W_ih = (const float*)d_in[1];
  const float* W_hh = (const float*)d_in[2];
  const float* b_ih = (const float*)d_in[3];
  const float* b_hh = (const float*)d_in[4];
  const float* fc_w = (const float*)d_in[5];
  const float* fc_b = (const float*)d_in[6];
  lstm_w4<<<BATCH/16, 256, 0, stream>>>(x, W_ih, W_hh, b_ih, b_hh, fc_w, fc_b,
                                        (float*)d_out);
}

// Round 4
// 573.125 us; speedup vs baseline: 4.6598x; 2.3948x over previous
//
#include <hip/hip_runtime.h>

#define SEQ   1024
#define BATCH 8192
#define HID   50
#define BT    16           // batch rows per block (16 = MFMA N)
#define CHS   16           // steps per x chunk
#define NCH   (SEQ/CHS)
#define CHF   (CHS*BT*3)   // 768 floats per chunk

typedef _Float16 half8 __attribute__((ext_vector_type(8)));
typedef float    f32x4 __attribute__((ext_vector_type(4)));

// state-fragment slot for value (k, batch b): layout [kh][grpk][b][i]
__device__ __forceinline__ int bslot(int k, int b){
  return (k >> 5)*512 + ((k & 31) >> 3)*128 + b*8 + (k & 7);
}

// chunk cg -> 3 regs; flat f = tid + 256u; step s = f/48, elem e = f%48
#define XLD(cg) {                                                         \
    const int f1 = tid + 256, f2 = tid + 512;                             \
    const int s0_ = (tid*683) >> 15, s1_ = (f1*683) >> 15,                \
              s2_ = (f2*683) >> 15;                                       \
    xr0 = x[(size_t)(((cg)*CHS + s0_)*BATCH + b0)*3 + (tid - 48*s0_)];    \
    xr1 = x[(size_t)(((cg)*CHS + s1_)*BATCH + b0)*3 + (f1  - 48*s1_)];    \
    xr2 = x[(size_t)(((cg)*CHS + s2_)*BATCH + b0)*3 + (f2  - 48*s2_)]; }

// all 4 gates of one item live in acc[0..3]; C tracks 2*log2e*c
#define ELEM(acc, C, slot) {                                                           \
    const float si = __builtin_amdgcn_rcpf(1.0f + __builtin_amdgcn_exp2f((acc)[0]));   \
    const float sf = __builtin_amdgcn_rcpf(1.0f + __builtin_amdgcn_exp2f((acc)[1]));   \
    const float rg = __builtin_amdgcn_rcpf(1.0f + __builtin_amdgcn_exp2f((acc)[2]));   \
    const float so = __builtin_amdgcn_rcpf(1.0f + __builtin_amdgcn_exp2f((acc)[3]));   \
    const float G  = __builtin_fmaf(-5.77078016355584f, rg, 2.88539008177792f);        \
    C = __builtin_fmaf(sf, C, si*G);                                                   \
    const float r2 = __builtin_amdgcn_rcpf(1.0f + __builtin_amdgcn_exp2f(C));          \
    const float u_ = so * r2;                                                          \
    const float h_ = __builtin_fmaf(-2.0f, u_, so);                                    \
    Bst[q][slot] = (_Float16)h_; }

__global__ __launch_bounds__(256, 2)
void lstm_wt(const float* __restrict__ x,
             const float* __restrict__ W_ih,
             const float* __restrict__ W_hh,
             const float* __restrict__ b_ih,
             const float* __restrict__ b_hh,
             const float* __restrict__ fc_w,
             const float* __restrict__ fc_b,
             float* __restrict__ out)
{
  // double-buffered state fragment [h | x | 1 | 0-pad] in MFMA-B layout (2 KB each)
  __shared__ _Float16 Bst[2][1024];
  __shared__ float    xb[2][CHF];     // x chunk double buffer

  const int tid  = threadIdx.x;
  const int w    = tid >> 6;
  const int lane = tid & 63;
  const int r16  = lane & 15;
  const int grp  = lane >> 4;
  const int b0   = blockIdx.x * BT;
  const float L2E = 1.44269504088896f;

  // ---- A fragments (weights): wave w owns tiles {w, w+4, w+8} (+12 for w==3)
  // A[m=tile*16+r16][k=kh*32+grp*8+i]; rows permuted c=4j+gate, pre-scaled:
  // gates i,f,o by -log2e (sigmoid via exp2), g by +2log2e (tanh via exp2)
  half8 Af[4][2];
  #pragma unroll
  for (int it = 0; it < 4; ++it) {
    const int tile = (it < 3) ? (w + 4*it) : 12;
    #pragma unroll
    for (int kh = 0; kh < 2; ++kh) {
      half8 f;
      #pragma unroll
      for (int i = 0; i < 8; ++i) {
        const int k = kh*32 + grp*8 + i;
        const int c = tile*16 + r16;
        float wv = 0.0f;
        if (c < 4*HID) {
          const int j = c >> 2, gi = c & 3;
          const int go = gi*HID + j;                     // i,f,g,o row order
          const float sc = (gi == 2) ? (2.0f*L2E) : (-L2E);
          if (k < HID)      wv = W_hh[go*HID + k] * sc;
          else if (k < 53)  wv = W_ih[go*3 + (k-50)] * sc;
          else if (k == 53) wv = (b_ih[go] + b_hh[go]) * sc;
        }
        f[i] = (_Float16)wv;
      }
      Af[it][kh] = f;
    }
  }

  // per-item h-write slots: item (b=r16, j) with j = w*4+grp+16*it (tile12: 48+grp)
  int wslot[4];
  #pragma unroll
  for (int it = 0; it < 4; ++it) {
    const int j = (it < 3) ? (w*4 + grp + 16*it) : (48 + grp);
    wslot[it] = bslot((j < HID) ? j : 0, r16);
  }

  // ---- init: zero both state buffers; set k=53 "1.0" bias slots ----
  for (int i = tid; i < 1024; i += 256) ((unsigned*)Bst)[i] = 0u;
  __syncthreads();
  if (tid < 32) Bst[tid >> 4][768 + (tid & 15)*8 + 5] = (_Float16)1.0f;

  // ---- x prologue: chunks 0,1 -> LDS; chunk 2 -> regs ----
  float xr0, xr1, xr2;
  XLD(0); xb[0][tid] = xr0; xb[0][tid+256] = xr1; xb[0][tid+512] = xr2;
  XLD(1); xb[1][tid] = xr0; xb[1][tid+256] = xr1; xb[1][tid+512] = xr2;
  XLD(2);
  __syncthreads();
  if (tid < 48) {                       // x for step 0 into Bst[0]
    const int bb = (tid*171) >> 9, e = tid - 3*bb;
    Bst[0][768 + bb*8 + 2 + e] = (_Float16)xb[0][tid];
  }
  __syncthreads();

  float cs0 = 0.f, cs1 = 0.f, cs2 = 0.f, cs3 = 0.f;

  auto step = [&](int t, int p, int q) {
    // shared state fragment (B operand): col b=r16, k=grp*8+i (+32 for s1)
    const half8 s0 = *(const half8*)&Bst[p][lane*8];
    const half8 s1 = *(const half8*)&Bst[p][512 + lane*8];
    f32x4 a0 = {0.f,0.f,0.f,0.f}, a1 = a0, a2 = a0;
    a0 = __builtin_amdgcn_mfma_f32_16x16x32_f16(Af[0][0], s0, a0, 0,0,0);
    a1 = __builtin_amdgcn_mfma_f32_16x16x32_f16(Af[1][0], s0, a1, 0,0,0);
    a2 = __builtin_amdgcn_mfma_f32_16x16x32_f16(Af[2][0], s0, a2, 0,0,0);
    a0 = __builtin_amdgcn_mfma_f32_16x16x32_f16(Af[0][1], s1, a0, 0,0,0);
    a1 = __builtin_amdgcn_mfma_f32_16x16x32_f16(Af[1][1], s1, a1, 0,0,0);
    a2 = __builtin_amdgcn_mfma_f32_16x16x32_f16(Af[2][1], s1, a2, 0,0,0);
    ELEM(a0, cs0, wslot[0]);
    ELEM(a1, cs1, wslot[1]);
    ELEM(a2, cs2, wslot[2]);
    if (w == 3) {                        // tile 12: j = 48+grp, valid for grp<2
      f32x4 a3 = {0.f,0.f,0.f,0.f};
      a3 = __builtin_amdgcn_mfma_f32_16x16x32_f16(Af[3][0], s0, a3, 0,0,0);
      a3 = __builtin_amdgcn_mfma_f32_16x16x32_f16(Af[3][1], s1, a3, 0,0,0);
      if (grp < 2) ELEM(a3, cs3, wslot[3]);
    }
    // x for step t+1 into the write buffer (wave 1 lanes 0..47)
    if ((unsigned)(tid - 64) < 48u) {
      const int xt = tid - 64;
      const int bb = (xt*171) >> 9, e = xt - 3*bb;
      const int tn = t + 1;
      Bst[q][768 + bb*8 + 2 + e] = (_Float16)xb[(tn >> 4) & 1][(tn & 15)*48 + xt];
    }
    // LDS-only barrier: do NOT drain vmcnt (x prefetch stays in flight)
    asm volatile("s_waitcnt lgkmcnt(0)\n\ts_barrier" ::: "memory");
  };

  #pragma unroll 1
  for (int tc = 0; tc < NCH; ++tc) {
    if (tc > 0) {
      const int pc = (tc + 1) & 1;      // commit chunk tc+1 (issued at tc-1)
      xb[pc][tid] = xr0; xb[pc][tid+256] = xr1; xb[pc][tid+512] = xr2;
      if (tc + 2 < NCH) { XLD(tc+2); }
    }
    const int tb = tc*CHS;
    #pragma unroll 1
    for (int u = 0; u < CHS/2; ++u) {
      step(tb + 2*u,     0, 1);
      step(tb + 2*u + 1, 1, 0);
    }
  }

  // ---- epilogue: h_1024 sits in Bst[0]; out[b] = fc_w . h + fc_b ----
  if (tid < BT) {
    float s = fc_b[0];
    #pragma unroll
    for (int j = 0; j < HID; ++j)
      s += fc_w[j] * (float)Bst[0][bslot(j, tid)];
    out[b0 + tid] = s;
  }
}

extern "C" void kernel_launch(void* const* d_in, const int* in_sizes, int n_in,
                              void* d_out, int out_size, void* d_ws, size_t ws_size,
                              hipStream_t stream)
{
  const float* x    = (const float*)d_in[0];
  const float* W_ih = (const float*)d_in[1];
  const float* W_hh = (const float*)d_in[2];
  const float* b_ih = (const float*)d_in[3];
  const float* b_hh = (const float*)d_in[4];
  const float* fc_w = (const float*)d_in[5];
  const float* fc_b = (const float*)d_in[6];
  lstm_wt<<<BATCH/BT, 256, 0, stream>>>(x, W_ih, W_hh, b_ih, b_hh, fc_w, fc_b,
                                        (float*)d_out);
}